// Round 5
// baseline (2517.619 us; speedup 1.0000x reference)
//
#include <hip/hip_runtime.h>
#include <hip/hip_bf16.h>

#define THREADS 256
#define SPB 8   // samples per block, one per 32-lane half-wave

__device__ __forceinline__ float fsig(float x){ return 1.0f / (1.0f + __expf(-x)); }
__device__ __forceinline__ float ftanh(float x){
    x = fminf(fmaxf(x, -12.0f), 12.0f);
    float e = __expf(2.0f * x);
    return (e - 1.0f) / (e + 1.0f);
}
// NaN-PROPAGATING leaky relu (fmaxf/fminf would flush NaN to 0 and mask bugs)
__device__ __forceinline__ float lrelu(float x){
    return x > 0.0f ? x : 0.01f * x;
}

__global__ void diag_kernel(float* outp, float code){
    outp[0] = code;
}

// 5-step LSTM recurrence; acc = gate pre-activations (xg + biases); h broadcast via half-wave shuffle
__device__ __forceinline__ void lstm_rec(const float (&wh)[4][32], const float (&acc)[5][4],
                                         float (&out)[5]){
    float h = 0.0f, c = 0.0f;
    #pragma unroll
    for (int t = 0; t < 5; ++t){
        float q0 = acc[t][0], q1 = acc[t][1], q2 = acc[t][2], q3 = acc[t][3];
        if (t > 0){
            #pragma unroll
            for (int k = 0; k < 32; ++k){
                float hk = __shfl(h, k, 32);   // broadcast h_k within the 32-lane half-wave
                q0 = fmaf(wh[0][k], hk, q0);
                q1 = fmaf(wh[1][k], hk, q1);
                q2 = fmaf(wh[2][k], hk, q2);
                q3 = fmaf(wh[3][k], hk, q3);
            }
        }
        float iv = fsig(q0), fv = fsig(q1), gv = ftanh(q2), ov = fsig(q3);
        c = fmaf(fv, c, iv * gv);
        h = ov * ftanh(c);
        out[t] = h;
    }
}

// LayerNorm over (T,H)=160 jointly + LeakyReLU, in place
__device__ __forceinline__ void ln_lrelu(float (&o)[5], const float* gs, const float* bs, int j){
    float s1 = 0.0f, s2 = 0.0f;
    #pragma unroll
    for (int t = 0; t < 5; ++t){ s1 += o[t]; s2 = fmaf(o[t], o[t], s2); }
    #pragma unroll
    for (int m = 1; m < 32; m <<= 1){
        s1 += __shfl_xor(s1, m, 64);   // masks <32 stay within the half-wave
        s2 += __shfl_xor(s2, m, 64);
    }
    float mu   = s1 * (1.0f/160.0f);
    float var  = s2 * (1.0f/160.0f) - mu*mu;
    float rstd = rsqrtf(var + 1e-5f);
    #pragma unroll
    for (int t = 0; t < 5; ++t){
        float y = (o[t] - mu) * rstd;
        y = fmaf(y, gs[t*32 + j], bs[t*32 + j]);
        o[t] = lrelu(y);
    }
}

__global__ void reslstm_kernel(const float* __restrict__ data,
                    const float* __restrict__ wih0, const float* __restrict__ whh0,
                    const float* __restrict__ bih0, const float* __restrict__ bhh0,
                    const float* __restrict__ g0p,  const float* __restrict__ be0p,
                    const float* __restrict__ wih1, const float* __restrict__ whh1,
                    const float* __restrict__ bih1, const float* __restrict__ bhh1,
                    const float* __restrict__ g1p,  const float* __restrict__ be1p,
                    const float* __restrict__ dwp,  const float* __restrict__ dbp,
                    float* __restrict__ outp, int Btot)
{
    __shared__ float xs[SPB*310];      // [s][t][62] fp32
    __shared__ float out0s[SPB*160];
    __shared__ float bias0s[128], bias1s[128];
    __shared__ float g0s[160], be0s[160], g1s[160], be1s[160];
    __shared__ float dws[480];
    __shared__ float dbs[3];

    const int tid = threadIdx.x;
    const int b0  = blockIdx.x * SPB;
    const int nsamp = (Btot - b0 < SPB) ? (Btot - b0) : SPB;

    // ---------------- stage (fp32) ----------------
    {
        const float* dat = data + (size_t)b0 * 310;   // sample chunk: idx = n*5 + t
        for (int i = tid; i < nsamp*310; i += THREADS){
            int s = i / 310, r = i - s*310;
            int n = r / 5,   t = r - n*5;
            xs[s*310 + t*62 + n] = dat[i];
        }
        if (tid < 128)  bias0s[tid] = bih0[tid] + bhh0[tid];
        else            { int q = tid - 128; bias1s[q] = bih1[q] + bhh1[q]; }
        if (tid < 160){
            g0s[tid] = g0p[tid];  be0s[tid] = be0p[tid];
            g1s[tid] = g1p[tid];  be1s[tid] = be1p[tid];
        }
        for (int i = tid; i < 480; i += THREADS) dws[i] = dwp[i];
        if (tid < 3) dbs[tid] = dbp[tid];
    }
    __syncthreads();

    const int j = tid & 31;       // hidden unit owned by this lane
    const int s = tid >> 5;       // sample-in-block (half-wave)

    // ---------------- phase A: xg0 = x @ W_ih0^T + biases ----------------
    float acc[5][4];
    #pragma unroll
    for (int r = 0; r < 4; ++r){
        float bv = bias0s[r*32 + j];
        #pragma unroll
        for (int t = 0; t < 5; ++t) acc[t][r] = bv;
    }
    {
        const float* xp = xs + s*310;
        for (int n = 0; n < 62; ++n){
            float w0 = wih0[(0*32 + j)*62 + n];
            float w1 = wih0[(1*32 + j)*62 + n];
            float w2 = wih0[(2*32 + j)*62 + n];
            float w3 = wih0[(3*32 + j)*62 + n];
            #pragma unroll
            for (int t = 0; t < 5; ++t){
                float xv = xp[t*62 + n];
                acc[t][0] = fmaf(w0, xv, acc[t][0]);
                acc[t][1] = fmaf(w1, xv, acc[t][1]);
                acc[t][2] = fmaf(w2, xv, acc[t][2]);
                acc[t][3] = fmaf(w3, xv, acc[t][3]);
            }
        }
    }

    // ---------------- layer 0 recurrence + LN + LeakyReLU ----------------
    float o0[5];
    {
        float wh[4][32];
        #pragma unroll
        for (int r = 0; r < 4; ++r)
            #pragma unroll
            for (int k = 0; k < 32; ++k)
                wh[r][k] = whh0[(r*32 + j)*32 + k];
        lstm_rec(wh, acc, o0);
    }
    ln_lrelu(o0, g0s, be0s, j);
    #pragma unroll
    for (int t = 0; t < 5; ++t) out0s[s*160 + t*32 + j] = o0[t];
    __syncthreads();

    // ---------------- phase B: xg1 = out0 @ W_ih1^T + biases ----------------
    #pragma unroll
    for (int r = 0; r < 4; ++r){
        float bv = bias1s[r*32 + j];
        #pragma unroll
        for (int t = 0; t < 5; ++t) acc[t][r] = bv;
    }
    {
        const float* op = out0s + s*160;
        for (int k = 0; k < 32; ++k){
            float w0 = wih1[(0*32 + j)*32 + k];
            float w1 = wih1[(1*32 + j)*32 + k];
            float w2 = wih1[(2*32 + j)*32 + k];
            float w3 = wih1[(3*32 + j)*32 + k];
            #pragma unroll
            for (int t = 0; t < 5; ++t){
                float ov = op[t*32 + k];
                acc[t][0] = fmaf(w0, ov, acc[t][0]);
                acc[t][1] = fmaf(w1, ov, acc[t][1]);
                acc[t][2] = fmaf(w2, ov, acc[t][2]);
                acc[t][3] = fmaf(w3, ov, acc[t][3]);
            }
        }
    }

    // ---------------- layer 1 recurrence + LN + residual ----------------
    float o1[5];
    {
        float wh[4][32];
        #pragma unroll
        for (int r = 0; r < 4; ++r)
            #pragma unroll
            for (int k = 0; k < 32; ++k)
                wh[r][k] = whh1[(r*32 + j)*32 + k];
        lstm_rec(wh, acc, o1);
    }
    ln_lrelu(o1, g1s, be1s, j);
    #pragma unroll
    for (int t = 0; t < 5; ++t) o1[t] += o0[t];   // residual

    // ---------------- dense head: (B,160) @ dw^T + db, LeakyReLU ----------------
    float p0 = 0.0f, p1 = 0.0f, p2 = 0.0f;
    #pragma unroll
    for (int t = 0; t < 5; ++t){
        float v = o1[t];
        p0 = fmaf(dws[      t*32 + j], v, p0);
        p1 = fmaf(dws[160 + t*32 + j], v, p1);
        p2 = fmaf(dws[320 + t*32 + j], v, p2);
    }
    #pragma unroll
    for (int m = 1; m < 32; m <<= 1){
        p0 += __shfl_xor(p0, m, 64);
        p1 += __shfl_xor(p1, m, 64);
        p2 += __shfl_xor(p2, m, 64);
    }
    if (j < 3 && s < nsamp){
        float v = (j == 0) ? p0 : ((j == 1) ? p1 : p2);
        v = lrelu(v + dbs[j]);
        outp[(size_t)(b0 + s)*3 + j] = v;
    }
}

extern "C" void kernel_launch(void* const* d_in, const int* in_sizes, int n_in,
                              void* d_out, int out_size, void* d_ws, size_t ws_size,
                              hipStream_t stream)
{
    (void)d_ws; (void)ws_size;

    const int B = out_size / 3;

    // Locate 'data' = largest input; infer the harness's input ordering from it.
    int idx_data = 0;
    for (int i = 1; i < n_in; ++i)
        if (in_sizes[i] > in_sizes[idx_data]) idx_data = i;

    // semantic slots (reference dict order):
    // 0 data,1 wih0,2 whh0,3 bih0,4 bhh0,5 g0,6 be0,7 wih1,8 whh1,9 bih1,
    // 10 bhh1,11 g1,12 be1,13 dw,14 db
    static const int dict_map[15]  = {0,1,2,3,4,5,6,7,8,9,10,11,12,13,14};
    // alphabetical key order: b_hh0,b_hh1,b_ih0,b_ih1,be0,be1,data,db,dw,g0,g1,w_hh0,w_hh1,w_ih0,w_ih1
    static const int alpha_map[15] = {6,13,11,2,0,9,4,14,12,3,1,10,5,8,7};
    static const int rev_map[15]   = {14,13,12,11,10,9,8,7,6,5,4,3,2,1,0};

    const int* map = dict_map;
    if (idx_data == 6)       map = alpha_map;
    else if (idx_data == 14) map = rev_map;

    // Sanity: data slot = B*310 elements (or byte-counted variants);
    // w_ih0 slot = 128*62 = 7936 (or byte-counted variants).
    long ds  = (long)in_sizes[idx_data];
    long ws0 = (long)in_sizes[map[1]];
    bool ok = (ds == (long)B*310 || ds == (long)B*620 || ds == (long)B*1240)
           && (ws0 == 7936 || ws0 == 15872 || ws0 == 31744);

    if (!ok || B <= 0){
        // Encode where 'data' landed into the output for diagnosis.
        diag_kernel<<<1, 1, 0, stream>>>((float*)d_out, 100.0f + 10.0f*idx_data);
        return;
    }

    const float* P[15];
    for (int k = 0; k < 15; ++k) P[k] = (const float*)d_in[map[k]];

    const int nblocks = (B + SPB - 1) / SPB;
    reslstm_kernel<<<dim3(nblocks), dim3(THREADS), 0, stream>>>(
        P[0], P[1], P[2], P[3], P[4], P[5], P[6], P[7], P[8], P[9],
        P[10], P[11], P[12], P[13], P[14],
        (float*)d_out, B);
}

// Round 6
// 1050.382 us; speedup vs baseline: 2.3969x; 2.3969x over previous
//
#include <hip/hip_runtime.h>
#include <hip/hip_bf16.h>

#define THREADS 256
#define SPB 8   // samples per block, one per 32-lane half-wave

__device__ __forceinline__ float fsig(float x){ return 1.0f / (1.0f + __expf(-x)); }
__device__ __forceinline__ float ftanh(float x){
    x = fminf(fmaxf(x, -12.0f), 12.0f);
    float e = __expf(2.0f * x);
    return (e - 1.0f) / (e + 1.0f);
}
// NaN-PROPAGATING leaky relu (fmaxf/fminf would flush NaN to 0 and mask bugs)
__device__ __forceinline__ float lrelu(float x){
    return x > 0.0f ? x : 0.01f * x;
}

__global__ void diag_kernel(float* outp, float code){
    outp[0] = code;
}

// load per-lane W_hh rows {j, 32+j, 64+j, 96+j} straight from global (L2-hot) as float4
__device__ __forceinline__ void load_wh_global(const float* __restrict__ whh, int j, float (&wh)[4][32]){
    #pragma unroll
    for (int r = 0; r < 4; ++r){
        const float* rp = whh + (r*32 + j)*32;
        #pragma unroll
        for (int q = 0; q < 8; ++q){
            float4 v = *(const float4*)(rp + q*4);
            wh[r][q*4+0] = v.x; wh[r][q*4+1] = v.y;
            wh[r][q*4+2] = v.z; wh[r][q*4+3] = v.w;
        }
    }
}

// 5-step LSTM recurrence; acc = gate pre-activations (xg + biases); h broadcast via half-wave shuffle
__device__ __forceinline__ void lstm_rec(const float (&wh)[4][32], const float (&acc)[5][4],
                                         float (&out)[5]){
    float h = 0.0f, c = 0.0f;
    #pragma unroll
    for (int t = 0; t < 5; ++t){
        float q0 = acc[t][0], q1 = acc[t][1], q2 = acc[t][2], q3 = acc[t][3];
        if (t > 0){
            #pragma unroll
            for (int k = 0; k < 32; ++k){
                float hk = __shfl(h, k, 32);   // broadcast h_k within the 32-lane half-wave
                q0 = fmaf(wh[0][k], hk, q0);
                q1 = fmaf(wh[1][k], hk, q1);
                q2 = fmaf(wh[2][k], hk, q2);
                q3 = fmaf(wh[3][k], hk, q3);
            }
        }
        float iv = fsig(q0), fv = fsig(q1), gv = ftanh(q2), ov = fsig(q3);
        c = fmaf(fv, c, iv * gv);
        h = ov * ftanh(c);
        out[t] = h;
    }
}

// LayerNorm over (T,H)=160 jointly + LeakyReLU, in place
__device__ __forceinline__ void ln_lrelu(float (&o)[5], const float* gs, const float* bs, int j){
    float s1 = 0.0f, s2 = 0.0f;
    #pragma unroll
    for (int t = 0; t < 5; ++t){ s1 += o[t]; s2 = fmaf(o[t], o[t], s2); }
    #pragma unroll
    for (int m = 1; m < 32; m <<= 1){
        s1 += __shfl_xor(s1, m, 64);   // masks <32 stay within the half-wave
        s2 += __shfl_xor(s2, m, 64);
    }
    float mu   = s1 * (1.0f/160.0f);
    float var  = s2 * (1.0f/160.0f) - mu*mu;
    float rstd = rsqrtf(var + 1e-5f);
    #pragma unroll
    for (int t = 0; t < 5; ++t){
        float y = (o[t] - mu) * rstd;
        y = fmaf(y, gs[t*32 + j], bs[t*32 + j]);
        o[t] = lrelu(y);
    }
}

__global__ __launch_bounds__(THREADS, 1)
void reslstm_kernel(const float* __restrict__ data,
                    const float* __restrict__ wih0, const float* __restrict__ whh0,
                    const float* __restrict__ bih0, const float* __restrict__ bhh0,
                    const float* __restrict__ g0p,  const float* __restrict__ be0p,
                    const float* __restrict__ wih1, const float* __restrict__ whh1,
                    const float* __restrict__ bih1, const float* __restrict__ bhh1,
                    const float* __restrict__ g1p,  const float* __restrict__ be1p,
                    const float* __restrict__ dwp,  const float* __restrict__ dbp,
                    float* __restrict__ outp, int Btot)
{
    // xs: [s][t][64], pad n=62,63 with 0; reads are half-wave broadcasts (no conflicts)
    __shared__ __attribute__((aligned(16))) float xs[SPB*320];
    // wbuf phase A: wih0 [128][68] (stride 68 floats = 272 B, 16B-aligned; 4-way bank alias max)
    // wbuf phase B: wih1 [128][36] (stride 36 floats = 144 B, 16B-aligned)
    __shared__ __attribute__((aligned(16))) float wbuf[128*68];
    __shared__ __attribute__((aligned(16))) float out0s[SPB*160];
    __shared__ float bias0s[128], bias1s[128];
    __shared__ float g0s[160], be0s[160], g1s[160], be1s[160];
    __shared__ float dws[480];
    __shared__ float dbs[3];

    const int tid = threadIdx.x;
    const int b0  = blockIdx.x * SPB;
    const int nsamp = (Btot - b0 < SPB) ? (Btot - b0) : SPB;

    // ---------------- stage (coalesced fp32 global -> LDS) ----------------
    {
        const float* dat = data + (size_t)b0 * 310;   // sample chunk: idx = n*5 + t
        for (int i = tid; i < nsamp*310; i += THREADS){
            int s = i / 310, r = i - s*310;
            int n = r / 5,   t = r - n*5;
            xs[s*320 + t*64 + n] = dat[i];
        }
        for (int i = tid; i < SPB*10; i += THREADS){          // zero pad n=62,63
            int s = i / 10, q = i - s*10;
            xs[s*320 + (q>>1)*64 + 62 + (q&1)] = 0.0f;
        }
        for (int i = tid; i < 128*62; i += THREADS){
            int row = i / 62, n = i - row*62;
            wbuf[row*68 + n] = wih0[i];
        }
        for (int i = tid; i < 128*6; i += THREADS){           // zero pad n=62..67
            int row = i / 6, n = i - row*6;
            wbuf[row*68 + 62 + n] = 0.0f;
        }
        if (tid < 128)  bias0s[tid] = bih0[tid] + bhh0[tid];
        else            { int q = tid - 128; bias1s[q] = bih1[q] + bhh1[q]; }
        if (tid < 160){
            g0s[tid] = g0p[tid];  be0s[tid] = be0p[tid];
            g1s[tid] = g1p[tid];  be1s[tid] = be1p[tid];
        }
        for (int i = tid; i < 480; i += THREADS) dws[i] = dwp[i];
        if (tid < 3) dbs[tid] = dbp[tid];
    }
    __syncthreads();

    const int j = tid & 31;       // hidden unit owned by this lane
    const int s = tid >> 5;       // sample-in-block (half-wave)

    // ---------------- phase A: xg0 = x @ W_ih0^T + biases (float4 LDS reads) ----------------
    float acc[5][4];
    #pragma unroll
    for (int r = 0; r < 4; ++r){
        float bv = bias0s[r*32 + j];
        #pragma unroll
        for (int t = 0; t < 5; ++t) acc[t][r] = bv;
    }
    {
        const float* xp  = xs   + s*320;
        const float* wp0 = wbuf + j*68;
        #pragma unroll 4
        for (int n0 = 0; n0 < 64; n0 += 4){
            float4 w[4];
            #pragma unroll
            for (int r = 0; r < 4; ++r)
                w[r] = *(const float4*)(wp0 + r*32*68 + n0);
            #pragma unroll
            for (int t = 0; t < 5; ++t){
                float4 xv = *(const float4*)(xp + t*64 + n0);
                #pragma unroll
                for (int r = 0; r < 4; ++r)
                    acc[t][r] = fmaf(w[r].x, xv.x, fmaf(w[r].y, xv.y, fmaf(w[r].z, xv.z, fmaf(w[r].w, xv.w, acc[t][r]))));
            }
        }
    }

    // ---------------- layer 0 recurrence + LN + LeakyReLU ----------------
    float o0[5];
    {
        float wh[4][32];
        load_wh_global(whh0, j, wh);
        lstm_rec(wh, acc, o0);
    }
    ln_lrelu(o0, g0s, be0s, j);
    #pragma unroll
    for (int t = 0; t < 5; ++t) out0s[s*160 + t*32 + j] = o0[t];

    __syncthreads();
    // ---------------- restage wih1 into wbuf [128][36] ----------------
    for (int i = tid; i < 128*32; i += THREADS){
        int row = i >> 5, k = i & 31;
        wbuf[row*36 + k] = wih1[i];
    }
    for (int i = tid; i < 128*4; i += THREADS){
        int row = i >> 2;
        wbuf[row*36 + 32 + (i & 3)] = 0.0f;
    }
    __syncthreads();

    // ---------------- phase B: xg1 = out0 @ W_ih1^T + biases ----------------
    #pragma unroll
    for (int r = 0; r < 4; ++r){
        float bv = bias1s[r*32 + j];
        #pragma unroll
        for (int t = 0; t < 5; ++t) acc[t][r] = bv;
    }
    {
        const float* wp1 = wbuf  + j*36;
        const float* op  = out0s + s*160;
        #pragma unroll 2
        for (int k0 = 0; k0 < 32; k0 += 4){
            float4 w[4];
            #pragma unroll
            for (int r = 0; r < 4; ++r)
                w[r] = *(const float4*)(wp1 + r*32*36 + k0);
            #pragma unroll
            for (int t = 0; t < 5; ++t){
                float4 ov = *(const float4*)(op + t*32 + k0);
                #pragma unroll
                for (int r = 0; r < 4; ++r)
                    acc[t][r] = fmaf(w[r].x, ov.x, fmaf(w[r].y, ov.y, fmaf(w[r].z, ov.z, fmaf(w[r].w, ov.w, acc[t][r]))));
            }
        }
    }

    // ---------------- layer 1 recurrence + LN + residual ----------------
    float o1[5];
    {
        float wh[4][32];
        load_wh_global(whh1, j, wh);
        lstm_rec(wh, acc, o1);
    }
    ln_lrelu(o1, g1s, be1s, j);
    #pragma unroll
    for (int t = 0; t < 5; ++t) o1[t] += o0[t];   // residual

    // ---------------- dense head: (B,160) @ dw^T + db, LeakyReLU ----------------
    float p0 = 0.0f, p1 = 0.0f, p2 = 0.0f;
    #pragma unroll
    for (int t = 0; t < 5; ++t){
        float v = o1[t];
        p0 = fmaf(dws[      t*32 + j], v, p0);
        p1 = fmaf(dws[160 + t*32 + j], v, p1);
        p2 = fmaf(dws[320 + t*32 + j], v, p2);
    }
    #pragma unroll
    for (int m = 1; m < 32; m <<= 1){
        p0 += __shfl_xor(p0, m, 64);
        p1 += __shfl_xor(p1, m, 64);
        p2 += __shfl_xor(p2, m, 64);
    }
    if (j < 3 && s < nsamp){
        float v = (j == 0) ? p0 : ((j == 1) ? p1 : p2);
        v = lrelu(v + dbs[j]);
        outp[(size_t)(b0 + s)*3 + j] = v;
    }
}

extern "C" void kernel_launch(void* const* d_in, const int* in_sizes, int n_in,
                              void* d_out, int out_size, void* d_ws, size_t ws_size,
                              hipStream_t stream)
{
    (void)d_ws; (void)ws_size;

    const int B = out_size / 3;

    // Locate 'data' = largest input; infer the harness's input ordering from it.
    int idx_data = 0;
    for (int i = 1; i < n_in; ++i)
        if (in_sizes[i] > in_sizes[idx_data]) idx_data = i;

    // semantic slots (reference dict order):
    // 0 data,1 wih0,2 whh0,3 bih0,4 bhh0,5 g0,6 be0,7 wih1,8 whh1,9 bih1,
    // 10 bhh1,11 g1,12 be1,13 dw,14 db
    static const int dict_map[15]  = {0,1,2,3,4,5,6,7,8,9,10,11,12,13,14};
    // alphabetical key order fallback
    static const int alpha_map[15] = {6,13,11,2,0,9,4,14,12,3,1,10,5,8,7};
    static const int rev_map[15]   = {14,13,12,11,10,9,8,7,6,5,4,3,2,1,0};

    const int* map = dict_map;
    if (idx_data == 6)       map = alpha_map;
    else if (idx_data == 14) map = rev_map;

    long ds  = (long)in_sizes[idx_data];
    long ws0 = (long)in_sizes[map[1]];
    bool ok = (ds == (long)B*310 || ds == (long)B*620 || ds == (long)B*1240)
           && (ws0 == 7936 || ws0 == 15872 || ws0 == 31744);

    if (!ok || B <= 0){
        diag_kernel<<<1, 1, 0, stream>>>((float*)d_out, 100.0f + 10.0f*idx_data);
        return;
    }

    const float* P[15];
    for (int k = 0; k < 15; ++k) P[k] = (const float*)d_in[map[k]];

    const int nblocks = (B + SPB - 1) / SPB;
    reslstm_kernel<<<dim3(nblocks), dim3(THREADS), 0, stream>>>(
        P[0], P[1], P[2], P[3], P[4], P[5], P[6], P[7], P[8], P[9],
        P[10], P[11], P[12], P[13], P[14],
        (float*)d_out, B);
}